// Round 1
// baseline (3022.724 us; speedup 1.0000x reference)
//
#include <hip/hip_runtime.h>

#define BATCH 16
#define NQ 1024
#define NK 384
#define DIM 768
#define RED 256
#define CATD 1536

// ---------------- tiled f32 GEMM: C = scale * A(MxK) . B(NxK)^T + bias ----------------
__global__ __launch_bounds__(256) void gemm_nt(
    const float* __restrict__ A, const float* __restrict__ Bm,
    float* __restrict__ C, const float* __restrict__ bias,
    int M, int N, int K, int lda, int ldb, int ldc,
    long sA, long sB, long sC, float scale)
{
    __shared__ float As[64][17];
    __shared__ float Bs[64][17];
    const int b = blockIdx.z;
    A += (long)b * sA; Bm += (long)b * sB; C += (long)b * sC;
    const int m0 = blockIdx.y * 64, n0 = blockIdx.x * 64;
    const int tid = threadIdx.x;
    const int tx = tid & 15, ty = tid >> 4;
    float acc[4][4] = {};
    for (int k0 = 0; k0 < K; k0 += 16) {
        #pragma unroll
        for (int i = 0; i < 4; i++) {
            int idx = tid + i * 256;
            int r = idx >> 4, c = idx & 15;
            As[r][c] = A[(long)(m0 + r) * lda + k0 + c];
            Bs[r][c] = Bm[(long)(n0 + r) * ldb + k0 + c];
        }
        __syncthreads();
        #pragma unroll
        for (int kk = 0; kk < 16; kk++) {
            float av[4], bv[4];
            #pragma unroll
            for (int i = 0; i < 4; i++) av[i] = As[ty * 4 + i][kk];
            #pragma unroll
            for (int j = 0; j < 4; j++) bv[j] = Bs[tx * 4 + j][kk];
            #pragma unroll
            for (int i = 0; i < 4; i++)
                #pragma unroll
                for (int j = 0; j < 4; j++)
                    acc[i][j] += av[i] * bv[j];
        }
        __syncthreads();
    }
    #pragma unroll
    for (int i = 0; i < 4; i++) {
        long m = m0 + ty * 4 + i;
        #pragma unroll
        for (int j = 0; j < 4; j++) {
            int n = n0 + tx * 4 + j;
            float v = acc[i][j] * scale;
            if (bias) v += bias[n];
            C[m * ldc + n] = v;
        }
    }
}

// ---------------- tiled f32 GEMM: C = A(MxK) . B(KxN) ----------------
__global__ __launch_bounds__(256) void gemm_nn(
    const float* __restrict__ A, const float* __restrict__ Bm,
    float* __restrict__ C,
    int M, int N, int K, int lda, int ldb, int ldc,
    long sA, long sB, long sC)
{
    __shared__ float As[64][17];
    __shared__ float Bs[16][65];
    const int b = blockIdx.z;
    A += (long)b * sA; Bm += (long)b * sB; C += (long)b * sC;
    const int m0 = blockIdx.y * 64, n0 = blockIdx.x * 64;
    const int tid = threadIdx.x;
    const int tx = tid & 15, ty = tid >> 4;
    float acc[4][4] = {};
    for (int k0 = 0; k0 < K; k0 += 16) {
        #pragma unroll
        for (int i = 0; i < 4; i++) {
            int idx = tid + i * 256;
            int r = idx >> 4, c = idx & 15;
            As[r][c] = A[(long)(m0 + r) * lda + k0 + c];
            int rb = idx >> 6, cb = idx & 63;
            Bs[rb][cb] = Bm[(long)(k0 + rb) * ldb + n0 + cb];
        }
        __syncthreads();
        #pragma unroll
        for (int kk = 0; kk < 16; kk++) {
            float av[4], bv[4];
            #pragma unroll
            for (int i = 0; i < 4; i++) av[i] = As[ty * 4 + i][kk];
            #pragma unroll
            for (int j = 0; j < 4; j++) bv[j] = Bs[kk][tx * 4 + j];
            #pragma unroll
            for (int i = 0; i < 4; i++)
                #pragma unroll
                for (int j = 0; j < 4; j++)
                    acc[i][j] += av[i] * bv[j];
        }
        __syncthreads();
    }
    #pragma unroll
    for (int i = 0; i < 4; i++) {
        long m = m0 + ty * 4 + i;
        #pragma unroll
        for (int j = 0; j < 4; j++) {
            int n = n0 + tx * 4 + j;
            C[m * ldc + n] = acc[i][j];
        }
    }
}

// ---------------- column sums over tokens (atomic partial) ----------------
__global__ __launch_bounds__(256) void colsum(
    const float* __restrict__ X, float* __restrict__ mean, int N, int chunk)
{
    int b = blockIdx.x;
    int d = blockIdx.y * 256 + threadIdx.x;
    int n0 = blockIdx.z * chunk;
    float s = 0.f;
    for (int n = n0; n < n0 + chunk; n++)
        s += X[((long)b * N + n) * DIM + d];
    atomicAdd(&mean[b * DIM + d], s);
}

// ---------------- subtract per-(b,d) token mean ----------------
__global__ __launch_bounds__(256) void subcenter(
    const float* __restrict__ X, const float* __restrict__ mean,
    float* __restrict__ Xc, int N, float invN)
{
    long i = (long)blockIdx.x * 256 + threadIdx.x;
    long total = (long)BATCH * N * DIM;
    if (i >= total) return;
    int d = (int)(i % DIM);
    long bn = i / DIM;
    int b = (int)(bn / N);
    Xc[i] = X[i] - mean[b * DIM + d] * invN;
}

// ---------------- row softmax in place; optional per-batch additive vector ----------------
__global__ __launch_bounds__(256) void softmax_rows(
    float* __restrict__ S, const float* __restrict__ addv,
    int L, int rows_per_batch)
{
    long row = blockIdx.x;
    float* p = S + row * (long)L;
    const int tid = threadIdx.x;
    __shared__ float red[4];
    float mx = -3.0e38f;
    for (int i = tid; i < L; i += 256) mx = fmaxf(mx, p[i]);
    #pragma unroll
    for (int o = 1; o < 64; o <<= 1) mx = fmaxf(mx, __shfl_xor(mx, o));
    if ((tid & 63) == 0) red[tid >> 6] = mx;
    __syncthreads();
    mx = fmaxf(fmaxf(red[0], red[1]), fmaxf(red[2], red[3]));
    float s = 0.f;
    for (int i = tid; i < L; i += 256) { float e = expf(p[i] - mx); p[i] = e; s += e; }
    #pragma unroll
    for (int o = 1; o < 64; o <<= 1) s += __shfl_xor(s, o);
    __syncthreads();
    if ((tid & 63) == 0) red[tid >> 6] = s;
    __syncthreads();
    s = red[0] + red[1] + red[2] + red[3];
    float inv = 1.0f / s;
    if (addv) {
        int b = (int)(row / rows_per_batch);
        const float* av = addv + (long)b * L;
        for (int i = tid; i < L; i += 256) p[i] = p[i] * inv + av[i];
    } else {
        for (int i = tid; i < L; i += 256) p[i] *= inv;
    }
}

// ---------------- hidden: h[b,n] = softmax_n( sum_m aw2[b,n,m]*lw[m] + lb ) ----------------
__global__ __launch_bounds__(384) void hidden_kernel(
    const float* __restrict__ aw2, const float* __restrict__ lw,
    const float* __restrict__ lb, float* __restrict__ hid)
{
    int b = blockIdx.x;
    int n = threadIdx.x; // 0..383
    const float* row = aw2 + ((long)b * NK + n) * NK;
    float s = lb[0];
    for (int m = 0; m < NK; m++) s += row[m] * lw[m];
    __shared__ float red[6];
    float mx = s;
    #pragma unroll
    for (int o = 1; o < 64; o <<= 1) mx = fmaxf(mx, __shfl_xor(mx, o));
    int wid = n >> 6;
    if ((n & 63) == 0) red[wid] = mx;
    __syncthreads();
    mx = red[0];
    #pragma unroll
    for (int w = 1; w < 6; w++) mx = fmaxf(mx, red[w]);
    float e = expf(s - mx);
    float sm = e;
    #pragma unroll
    for (int o = 1; o < 64; o <<= 1) sm += __shfl_xor(sm, o);
    __syncthreads();
    if ((n & 63) == 0) red[wid] = sm;
    __syncthreads();
    sm = 0.f;
    #pragma unroll
    for (int w = 0; w < 6; w++) sm += red[w];
    hid[b * NK + n] = e / sm;
}

extern "C" void kernel_launch(void* const* d_in, const int* in_sizes, int n_in,
                              void* d_out, int out_size, void* d_ws, size_t ws_size,
                              hipStream_t stream)
{
    const float* Qf  = (const float*)d_in[0];
    const float* If  = (const float*)d_in[1];
    const float* Wq1 = (const float*)d_in[2];
    const float* Wq2 = (const float*)d_in[4];
    const float* Wq3 = (const float*)d_in[6];
    const float* Wk1 = (const float*)d_in[8];
    const float* Wk2 = (const float*)d_in[10];
    const float* Wk3 = (const float*)d_in[12];
    const float* lw  = (const float*)d_in[14];
    const float* lb  = (const float*)d_in[15];
    const float* Wout= (const float*)d_in[16];
    const float* bout= (const float*)d_in[17];

    float* cat = (float*)d_out;                              // [B,NQ,1536]
    float* out = (float*)d_out + (long)BATCH * NQ * CATD;    // [B,NQ,768]

    float* ws = (float*)d_ws;
    size_t off = 0;
    float* Qc = ws + off; off += (size_t)BATCH * NQ * DIM;
    float* Kc = ws + off; off += (size_t)BATCH * NK * DIM;
    float* q1 = ws + off; off += (size_t)BATCH * NQ * RED;
    float* q2 = ws + off; off += (size_t)BATCH * NQ * RED;
    float* q3 = ws + off; off += (size_t)BATCH * NQ * RED;
    float* k1 = ws + off; off += (size_t)BATCH * NK * RED;
    float* k2 = ws + off; off += (size_t)BATCH * NK * RED;
    float* k3 = ws + off; off += (size_t)BATCH * NK * RED;
    float* S1 = ws + off; off += (size_t)BATCH * NQ * NQ;
    float* S2 = ws + off; off += (size_t)BATCH * NK * NK;
    float* S3 = ws + off; off += (size_t)BATCH * NQ * NK;
    float* meanQ = ws + off; off += (size_t)BATCH * DIM;
    float* meanK = ws + off; off += (size_t)BATCH * DIM;
    float* hid   = ws + off; off += (size_t)BATCH * NK;

    // zero the mean accumulators (meanQ and meanK are contiguous)
    hipMemsetAsync(meanQ, 0, (size_t)BATCH * DIM * 2 * sizeof(float), stream);

    // token-mean of inputs
    colsum<<<dim3(BATCH, DIM / 256, NQ / 128), 256, 0, stream>>>(Qf, meanQ, NQ, 128);
    colsum<<<dim3(BATCH, DIM / 256, NK / 128), 256, 0, stream>>>(If, meanK, NK, 128);
    subcenter<<<(BATCH * NQ * DIM) / 256, 256, 0, stream>>>(Qf, meanQ, Qc, NQ, 1.0f / NQ);
    subcenter<<<(BATCH * NK * DIM) / 256, 256, 0, stream>>>(If, meanK, Kc, NK, 1.0f / NK);

    // projections (bias cancels under mean-centering)
    dim3 gq(RED / 64, NQ / 64, BATCH), gk(RED / 64, NK / 64, BATCH);
    gemm_nt<<<gq, 256, 0, stream>>>(Qc, Wq1, q1, nullptr, NQ, RED, DIM, DIM, DIM, RED,
                                    (long)NQ * DIM, 0, (long)NQ * RED, 1.0f);
    gemm_nt<<<gq, 256, 0, stream>>>(Qc, Wq2, q2, nullptr, NQ, RED, DIM, DIM, DIM, RED,
                                    (long)NQ * DIM, 0, (long)NQ * RED, 1.0f);
    gemm_nt<<<gq, 256, 0, stream>>>(Qc, Wq3, q3, nullptr, NQ, RED, DIM, DIM, DIM, RED,
                                    (long)NQ * DIM, 0, (long)NQ * RED, 1.0f);
    gemm_nt<<<gk, 256, 0, stream>>>(Kc, Wk1, k1, nullptr, NK, RED, DIM, DIM, DIM, RED,
                                    (long)NK * DIM, 0, (long)NK * RED, 1.0f);
    gemm_nt<<<gk, 256, 0, stream>>>(Kc, Wk2, k2, nullptr, NK, RED, DIM, DIM, DIM, RED,
                                    (long)NK * DIM, 0, (long)NK * RED, 1.0f);
    gemm_nt<<<gk, 256, 0, stream>>>(Kc, Wk3, k3, nullptr, NK, RED, DIM, DIM, DIM, RED,
                                    (long)NK * DIM, 0, (long)NK * RED, 1.0f);

    const float scale = 0.0625f; // 1/sqrt(256)

    // aw1 = softmax(q1.q2^T * s)
    gemm_nt<<<dim3(NQ / 64, NQ / 64, BATCH), 256, 0, stream>>>(
        q1, q2, S1, nullptr, NQ, NQ, RED, RED, RED, NQ,
        (long)NQ * RED, (long)NQ * RED, (long)NQ * NQ, scale);
    softmax_rows<<<BATCH * NQ, 256, 0, stream>>>(S1, nullptr, NQ, NQ);

    // aw2 = softmax(k1.k2^T * s)
    gemm_nt<<<dim3(NK / 64, NK / 64, BATCH), 256, 0, stream>>>(
        k1, k2, S2, nullptr, NK, NK, RED, RED, RED, NK,
        (long)NK * RED, (long)NK * RED, (long)NK * NK, scale);
    softmax_rows<<<BATCH * NK, 256, 0, stream>>>(S2, nullptr, NK, NK);

    // hidden = softmax_n(aw2 @ lw + lb)
    hidden_kernel<<<BATCH, NK, 0, stream>>>(S2, lw, lb, hid);

    // aw3 = softmax(q3.k3^T * s) + hidden broadcast
    gemm_nt<<<dim3(NK / 64, NQ / 64, BATCH), 256, 0, stream>>>(
        q3, k3, S3, nullptr, NQ, NK, RED, RED, RED, NK,
        (long)NQ * RED, (long)NK * RED, (long)NQ * NK, scale);
    softmax_rows<<<BATCH * NQ, 256, 0, stream>>>(S3, hid, NK, NQ);

    // attention_feature1 = aw1 @ Qf -> cat[:, :768]
    gemm_nn<<<dim3(DIM / 64, NQ / 64, BATCH), 256, 0, stream>>>(
        S1, Qf, cat, NQ, DIM, NQ, NQ, DIM, CATD,
        (long)NQ * NQ, (long)NQ * DIM, (long)NQ * CATD);
    // attention_feature2 = (aw3+hidden) @ If -> cat[:, 768:]
    gemm_nn<<<dim3(DIM / 64, NQ / 64, BATCH), 256, 0, stream>>>(
        S3, If, cat + DIM, NQ, DIM, NK, NK, DIM, CATD,
        (long)NQ * NK, (long)NK * DIM, (long)NQ * CATD);

    // out = cat @ Wout^T + bout
    gemm_nt<<<dim3(DIM / 64, NQ / 64, BATCH), 256, 0, stream>>>(
        cat, Wout, out, bout, NQ, DIM, CATD, CATD, CATD, DIM,
        (long)NQ * CATD, 0, (long)NQ * DIM, 1.0f);
}

// Round 2
// 794.685 us; speedup vs baseline: 3.8037x; 3.8037x over previous
//
#include <hip/hip_runtime.h>

#define BATCH 16
#define NQ 1024
#define NK 384
#define DIM 768
#define RED 256
#define CATD 1536

typedef __attribute__((ext_vector_type(4))) float f32x4;
typedef __attribute__((ext_vector_type(8))) short short8;

__device__ __forceinline__ short f2bf(float f) {
    unsigned u = __builtin_bit_cast(unsigned, f);
    u = (u + 0x7FFF + ((u >> 16) & 1)) >> 16;
    return (short)u;
}
__device__ __forceinline__ float bf2f(short s) {
    unsigned u = ((unsigned)(unsigned short)s) << 16;
    return __builtin_bit_cast(float, u);
}

#define GLOAD_LDS16(g, l) __builtin_amdgcn_global_load_lds( \
    (const __attribute__((address_space(1))) unsigned int*)(g), \
    (__attribute__((address_space(3))) unsigned int*)(l), 16, 0, 0)

// ---------------------------------------------------------------------------
// bf16 MFMA NT GEMM: C = scale * A(MxK) . B(NxK)^T [+ bias]
// A, B bf16 row-major (lda/ldb = row stride). 128x128 tile, BK=64, 256 thr.
// MODE 0: f32 out; 1: bf16 out; 2: dual f32+bf16; 3: f32 + bias
// ---------------------------------------------------------------------------
template<int MODE>
__global__ __launch_bounds__(256) void gemm_nt_mfma(
    const short* __restrict__ A, const short* __restrict__ B,
    float* __restrict__ Cf, short* __restrict__ Cb,
    const float* __restrict__ bias,
    int K, int lda, int ldb, int ldcf, int ldcb,
    long sA, long sB, long sCf, long sCb, float scale)
{
    __shared__ short Asl[128 * 64];
    __shared__ short Bsl[128 * 64];
    const int b = blockIdx.z;
    const short* Ab = A + (long)b * sA;
    const short* Bb = B + (long)b * sB;
    const int m0 = blockIdx.y * 128, n0 = blockIdx.x * 128;
    const int tid = threadIdx.x;
    const int lane = tid & 63, wid = tid >> 6;
    const int am0 = (wid >> 1) * 64, bn0 = (wid & 1) * 64;
    const int lr = lane & 15, lg = lane >> 4;

    f32x4 acc[4][4] = {};

    for (int k0 = 0; k0 < K; k0 += 64) {
        #pragma unroll
        for (int i = 0; i < 4; i++) {
            int e = (tid + i * 256) * 8;     // bf16 element offset within tile
            int r = e >> 6, c = e & 63;
            GLOAD_LDS16(Ab + (long)(m0 + r) * lda + k0 + c, Asl + e);
        }
        #pragma unroll
        for (int i = 0; i < 4; i++) {
            int e = (tid + i * 256) * 8;
            int r = e >> 6, c = e & 63;
            GLOAD_LDS16(Bb + (long)(n0 + r) * ldb + k0 + c, Bsl + e);
        }
        __syncthreads();
        #pragma unroll
        for (int ks = 0; ks < 2; ks++) {
            short8 af[4], bfv[4];
            #pragma unroll
            for (int m = 0; m < 4; m++)
                af[m] = *(const short8*)&Asl[(am0 + m * 16 + lr) * 64 + ks * 32 + lg * 8];
            #pragma unroll
            for (int n = 0; n < 4; n++)
                bfv[n] = *(const short8*)&Bsl[(bn0 + n * 16 + lr) * 64 + ks * 32 + lg * 8];
            #pragma unroll
            for (int m = 0; m < 4; m++)
                #pragma unroll
                for (int n = 0; n < 4; n++)
                    acc[m][n] = __builtin_amdgcn_mfma_f32_16x16x32_bf16(
                        af[m], bfv[n], acc[m][n], 0, 0, 0);
        }
        __syncthreads();
    }

    float* Cfb = (MODE != 1) ? Cf + (long)b * sCf : nullptr;
    short* Cbb = (MODE == 1 || MODE == 2) ? Cb + (long)b * sCb : nullptr;
    #pragma unroll
    for (int m = 0; m < 4; m++) {
        #pragma unroll
        for (int n = 0; n < 4; n++) {
            int col = n0 + bn0 + n * 16 + lr;
            #pragma unroll
            for (int j = 0; j < 4; j++) {
                long row = m0 + am0 + m * 16 + lg * 4 + j;
                float v = acc[m][n][j] * scale;
                if (MODE == 3) v += bias[col];
                if (MODE != 1) Cfb[row * ldcf + col] = v;
                if (MODE == 1 || MODE == 2) Cbb[row * ldcb + col] = f2bf(v);
            }
        }
    }
}

// ---------------- column sums over tokens (atomic partial) ----------------
__global__ __launch_bounds__(256) void colsum(
    const float* __restrict__ X, float* __restrict__ mean, int N, int chunk)
{
    int b = blockIdx.x;
    int d = blockIdx.y * 256 + threadIdx.x;
    int n0 = blockIdx.z * chunk;
    float s = 0.f;
    for (int n = n0; n < n0 + chunk; n++)
        s += X[((long)b * N + n) * DIM + d];
    atomicAdd(&mean[b * DIM + d], s);
}

// ---------------- center + convert to bf16 ----------------
__global__ __launch_bounds__(256) void center_cvt(
    const float* __restrict__ X, const float* __restrict__ mean,
    short* __restrict__ Xc, int N, float invN)
{
    long i = (long)blockIdx.x * 256 + threadIdx.x;
    long tot8 = (long)BATCH * N * DIM / 8;
    if (i >= tot8) return;
    long e = i * 8;
    int d = (int)(e % DIM);
    int b = (int)(e / ((long)N * DIM));
    const float* mb = mean + b * DIM + d;
    const f32x4* s = (const f32x4*)(X + e);
    f32x4 x0 = s[0], x1 = s[1];
    short8 o;
    o[0] = f2bf(x0[0] - mb[0] * invN);
    o[1] = f2bf(x0[1] - mb[1] * invN);
    o[2] = f2bf(x0[2] - mb[2] * invN);
    o[3] = f2bf(x0[3] - mb[3] * invN);
    o[4] = f2bf(x1[0] - mb[4] * invN);
    o[5] = f2bf(x1[1] - mb[5] * invN);
    o[6] = f2bf(x1[2] - mb[6] * invN);
    o[7] = f2bf(x1[3] - mb[7] * invN);
    *(short8*)(Xc + e) = o;
}

// ---------------- plain f32 -> bf16 convert ----------------
__global__ __launch_bounds__(256) void cvt_bf(
    const float* __restrict__ src, short* __restrict__ dst, int n8)
{
    int i = blockIdx.x * 256 + threadIdx.x;
    if (i >= n8) return;
    const f32x4* s = (const f32x4*)(src + (long)i * 8);
    f32x4 x0 = s[0], x1 = s[1];
    short8 o;
    o[0] = f2bf(x0[0]); o[1] = f2bf(x0[1]); o[2] = f2bf(x0[2]); o[3] = f2bf(x0[3]);
    o[4] = f2bf(x1[0]); o[5] = f2bf(x1[1]); o[6] = f2bf(x1[2]); o[7] = f2bf(x1[3]);
    *(short8*)(dst + (long)i * 8) = o;
}

// ---------------- transpose + convert: XT[b,d,n] = bf16(X[b,n,d]) ----------------
__global__ __launch_bounds__(256) void transpose_cvt(
    const float* __restrict__ X, short* __restrict__ XT, int N)
{
    __shared__ short tile[32][33];
    int b = blockIdx.z;
    int n0 = blockIdx.x * 32, d0 = blockIdx.y * 32;
    int tx = threadIdx.x & 31, ty = threadIdx.x >> 5;
    const float* Xb = X + (long)b * N * DIM;
    #pragma unroll
    for (int i = 0; i < 4; i++) {
        int n = n0 + ty + i * 8;
        tile[ty + i * 8][tx] = f2bf(Xb[(long)n * DIM + d0 + tx]);
    }
    __syncthreads();
    short* XTb = XT + (long)b * DIM * N;
    #pragma unroll
    for (int i = 0; i < 4; i++) {
        int d = d0 + ty + i * 8;
        XTb[(long)d * N + n0 + tx] = tile[tx][ty + i * 8];
    }
}

// ---------------- row softmax: S f32 (scratch, exp'ed in place) -> P bf16 ----------------
__global__ __launch_bounds__(256) void softmax_rows_bf(
    float* __restrict__ S, short* __restrict__ P,
    const float* __restrict__ addv, int L, int rows_per_batch)
{
    long row = blockIdx.x;
    float* p = S + row * (long)L;
    short* po = P + row * (long)L;
    const int tid = threadIdx.x;
    __shared__ float red[4];
    float mx = -3.0e38f;
    for (int i = tid; i < L; i += 256) mx = fmaxf(mx, p[i]);
    #pragma unroll
    for (int o = 1; o < 64; o <<= 1) mx = fmaxf(mx, __shfl_xor(mx, o));
    if ((tid & 63) == 0) red[tid >> 6] = mx;
    __syncthreads();
    mx = fmaxf(fmaxf(red[0], red[1]), fmaxf(red[2], red[3]));
    float s = 0.f;
    for (int i = tid; i < L; i += 256) { float e = expf(p[i] - mx); p[i] = e; s += e; }
    #pragma unroll
    for (int o = 1; o < 64; o <<= 1) s += __shfl_xor(s, o);
    __syncthreads();
    if ((tid & 63) == 0) red[tid >> 6] = s;
    __syncthreads();
    s = red[0] + red[1] + red[2] + red[3];
    float inv = 1.0f / s;
    if (addv) {
        int b = (int)(row / rows_per_batch);
        const float* av = addv + (long)b * L;
        for (int i = tid; i < L; i += 256) po[i] = f2bf(p[i] * inv + av[i]);
    } else {
        for (int i = tid; i < L; i += 256) po[i] = f2bf(p[i] * inv);
    }
}

// ---------------- hidden: h[b,n] = softmax_n( P2[b,n,:].lw + lb ) ----------------
__global__ __launch_bounds__(384) void hidden_kernel(
    const short* __restrict__ P2, const float* __restrict__ lw,
    const float* __restrict__ lb, float* __restrict__ hid)
{
    int b = blockIdx.x;
    int n = threadIdx.x; // 0..383
    const short* row = P2 + ((long)b * NK + n) * NK;
    float s = lb[0];
    for (int m = 0; m < NK; m++) s += bf2f(row[m]) * lw[m];
    __shared__ float red[6];
    float mx = s;
    #pragma unroll
    for (int o = 1; o < 64; o <<= 1) mx = fmaxf(mx, __shfl_xor(mx, o));
    int wid = n >> 6;
    if ((n & 63) == 0) red[wid] = mx;
    __syncthreads();
    mx = red[0];
    #pragma unroll
    for (int w = 1; w < 6; w++) mx = fmaxf(mx, red[w]);
    float e = expf(s - mx);
    float sm = e;
    #pragma unroll
    for (int o = 1; o < 64; o <<= 1) sm += __shfl_xor(sm, o);
    __syncthreads();
    if ((n & 63) == 0) red[wid] = sm;
    __syncthreads();
    sm = 0.f;
    #pragma unroll
    for (int w = 0; w < 6; w++) sm += red[w];
    hid[b * NK + n] = e / sm;
}

extern "C" void kernel_launch(void* const* d_in, const int* in_sizes, int n_in,
                              void* d_out, int out_size, void* d_ws, size_t ws_size,
                              hipStream_t stream)
{
    const float* Qf  = (const float*)d_in[0];
    const float* If  = (const float*)d_in[1];
    const float* Wq1 = (const float*)d_in[2];
    const float* Wq2 = (const float*)d_in[4];
    const float* Wq3 = (const float*)d_in[6];
    const float* Wk1 = (const float*)d_in[8];
    const float* Wk2 = (const float*)d_in[10];
    const float* Wk3 = (const float*)d_in[12];
    const float* lw  = (const float*)d_in[14];
    const float* lb  = (const float*)d_in[15];
    const float* Wout= (const float*)d_in[16];
    const float* bout= (const float*)d_in[17];

    float* cat = (float*)d_out;                              // [B,NQ,1536]
    float* out = (float*)d_out + (long)BATCH * NQ * CATD;    // [B,NQ,768]

    char* ws = (char*)d_ws;
    size_t off = 0;
    auto alloc = [&](size_t bytes) { char* p = ws + off; off += (bytes + 255) & ~(size_t)255; return p; };

    float* S     = (float*)alloc((size_t)BATCH * NQ * NQ * 4);   // reused S1/S2/S3
    short* Qc    = (short*)alloc((size_t)BATCH * NQ * DIM * 2);  // later aliased as QfT
    short* Kc    = (short*)alloc((size_t)BATCH * NK * DIM * 2);  // later aliased as IfT
    short* q1    = (short*)alloc((size_t)BATCH * NQ * RED * 2);
    short* q2    = (short*)alloc((size_t)BATCH * NQ * RED * 2);
    short* q3    = (short*)alloc((size_t)BATCH * NQ * RED * 2);
    short* k1    = (short*)alloc((size_t)BATCH * NK * RED * 2);
    short* k2    = (short*)alloc((size_t)BATCH * NK * RED * 2);
    short* k3    = (short*)alloc((size_t)BATCH * NK * RED * 2);
    short* P1    = (short*)alloc((size_t)BATCH * NQ * NQ * 2);
    short* P2    = (short*)alloc((size_t)BATCH * NK * NK * 2);
    short* P3    = (short*)alloc((size_t)BATCH * NQ * NK * 2);
    short* catbf = (short*)alloc((size_t)BATCH * NQ * CATD * 2);
    short* Wb    = (short*)alloc((size_t)6 * RED * DIM * 2);     // 6 proj weights
    short* WoutB = (short*)alloc((size_t)DIM * CATD * 2);
    float* means = (float*)alloc((size_t)2 * BATCH * DIM * 4);   // meanQ | meanK
    float* hid   = (float*)alloc((size_t)BATCH * NK * 4);

    float* meanQ = means;
    float* meanK = means + BATCH * DIM;
    short* Wq1b = Wb + 0 * RED * DIM;
    short* Wq2b = Wb + 1 * RED * DIM;
    short* Wq3b = Wb + 2 * RED * DIM;
    short* Wk1b = Wb + 3 * RED * DIM;
    short* Wk2b = Wb + 4 * RED * DIM;
    short* Wk3b = Wb + 5 * RED * DIM;
    short* QfT = Qc;  // [B, DIM, NQ] — alias, Qc dead after projections
    short* IfT = Kc;  // [B, DIM, NK]

    hipMemsetAsync(means, 0, (size_t)2 * BATCH * DIM * 4, stream);

    // means of raw inputs over token axis
    colsum<<<dim3(BATCH, DIM / 256, NQ / 128), 256, 0, stream>>>(Qf, meanQ, NQ, 128);
    colsum<<<dim3(BATCH, DIM / 256, NK / 128), 256, 0, stream>>>(If, meanK, NK, 128);
    // centered bf16 inputs (bias cancels under centering)
    center_cvt<<<(BATCH * NQ * DIM / 8 + 255) / 256, 256, 0, stream>>>(Qf, meanQ, Qc, NQ, 1.0f / NQ);
    center_cvt<<<(BATCH * NK * DIM / 8 + 255) / 256, 256, 0, stream>>>(If, meanK, Kc, NK, 1.0f / NK);

    // weights -> bf16
    const int wn8 = RED * DIM / 8;
    cvt_bf<<<(wn8 + 255) / 256, 256, 0, stream>>>(Wq1, Wq1b, wn8);
    cvt_bf<<<(wn8 + 255) / 256, 256, 0, stream>>>(Wq2, Wq2b, wn8);
    cvt_bf<<<(wn8 + 255) / 256, 256, 0, stream>>>(Wq3, Wq3b, wn8);
    cvt_bf<<<(wn8 + 255) / 256, 256, 0, stream>>>(Wk1, Wk1b, wn8);
    cvt_bf<<<(wn8 + 255) / 256, 256, 0, stream>>>(Wk2, Wk2b, wn8);
    cvt_bf<<<(wn8 + 255) / 256, 256, 0, stream>>>(Wk3, Wk3b, wn8);
    const int on8 = DIM * CATD / 8;
    cvt_bf<<<(on8 + 255) / 256, 256, 0, stream>>>(Wout, WoutB, on8);

    // projections: x(M x 768) . W(256 x 768)^T -> bf16 [M,256]
    dim3 gq(RED / 128, NQ / 128, BATCH), gk(RED / 128, NK / 128, BATCH);
    gemm_nt_mfma<1><<<gq, 256, 0, stream>>>(Qc, Wq1b, nullptr, q1, nullptr,
        DIM, DIM, DIM, 0, RED, (long)NQ * DIM, 0, 0, (long)NQ * RED, 1.0f);
    gemm_nt_mfma<1><<<gq, 256, 0, stream>>>(Qc, Wq2b, nullptr, q2, nullptr,
        DIM, DIM, DIM, 0, RED, (long)NQ * DIM, 0, 0, (long)NQ * RED, 1.0f);
    gemm_nt_mfma<1><<<gq, 256, 0, stream>>>(Qc, Wq3b, nullptr, q3, nullptr,
        DIM, DIM, DIM, 0, RED, (long)NQ * DIM, 0, 0, (long)NQ * RED, 1.0f);
    gemm_nt_mfma<1><<<gk, 256, 0, stream>>>(Kc, Wk1b, nullptr, k1, nullptr,
        DIM, DIM, DIM, 0, RED, (long)NK * DIM, 0, 0, (long)NK * RED, 1.0f);
    gemm_nt_mfma<1><<<gk, 256, 0, stream>>>(Kc, Wk2b, nullptr, k2, nullptr,
        DIM, DIM, DIM, 0, RED, (long)NK * DIM, 0, 0, (long)NK * RED, 1.0f);
    gemm_nt_mfma<1><<<gk, 256, 0, stream>>>(Kc, Wk3b, nullptr, k3, nullptr,
        DIM, DIM, DIM, 0, RED, (long)NK * DIM, 0, 0, (long)NK * RED, 1.0f);

    // transposed raw inputs for PV (overwrites Qc/Kc — dead after projections)
    transpose_cvt<<<dim3(NQ / 32, DIM / 32, BATCH), 256, 0, stream>>>(Qf, QfT, NQ);
    transpose_cvt<<<dim3(NK / 32, DIM / 32, BATCH), 256, 0, stream>>>(If, IfT, NK);

    const float scale = 0.0625f; // 1/sqrt(256)

    // aw1 = softmax(q1.q2^T/16) -> P1 bf16
    gemm_nt_mfma<0><<<dim3(NQ / 128, NQ / 128, BATCH), 256, 0, stream>>>(
        q1, q2, S, nullptr, nullptr, RED, RED, RED, NQ, 0,
        (long)NQ * RED, (long)NQ * RED, (long)NQ * NQ, 0, scale);
    softmax_rows_bf<<<BATCH * NQ, 256, 0, stream>>>(S, P1, nullptr, NQ, NQ);

    // aw2 = softmax(k1.k2^T/16) -> P2 bf16 (reuse S)
    gemm_nt_mfma<0><<<dim3(NK / 128, NK / 128, BATCH), 256, 0, stream>>>(
        k1, k2, S, nullptr, nullptr, RED, RED, RED, NK, 0,
        (long)NK * RED, (long)NK * RED, (long)NK * NK, 0, scale);
    softmax_rows_bf<<<BATCH * NK, 256, 0, stream>>>(S, P2, nullptr, NK, NK);

    // hidden = softmax_n(P2 @ lw + lb)
    hidden_kernel<<<BATCH, NK, 0, stream>>>(P2, lw, lb, hid);

    // aw3 = softmax(q3.k3^T/16) + hid -> P3 bf16 (reuse S)
    gemm_nt_mfma<0><<<dim3(NK / 128, NQ / 128, BATCH), 256, 0, stream>>>(
        q3, k3, S, nullptr, nullptr, RED, RED, RED, NK, 0,
        (long)NQ * RED, (long)NK * RED, (long)NQ * NK, 0, scale);
    softmax_rows_bf<<<BATCH * NQ, 256, 0, stream>>>(S, P3, hid, NK, NQ);

    // attention_feature1 = P1 . QfT^T -> cat[:, :768] (f32) + catbf
    gemm_nt_mfma<2><<<dim3(DIM / 128, NQ / 128, BATCH), 256, 0, stream>>>(
        P1, QfT, cat, catbf, nullptr, NQ, NQ, NQ, CATD, CATD,
        (long)NQ * NQ, (long)DIM * NQ, (long)NQ * CATD, (long)NQ * CATD, 1.0f);
    // attention_feature2 = P3 . IfT^T -> cat[:, 768:] + catbf
    gemm_nt_mfma<2><<<dim3(DIM / 128, NQ / 128, BATCH), 256, 0, stream>>>(
        P3, IfT, cat + DIM, catbf + DIM, nullptr, NK, NK, NK, CATD, CATD,
        (long)NQ * NK, (long)DIM * NK, (long)NQ * CATD, (long)NQ * CATD, 1.0f);

    // out = catbf . Wout^T + bout
    gemm_nt_mfma<3><<<dim3(DIM / 128, NQ / 128, BATCH), 256, 0, stream>>>(
        catbf, WoutB, out, nullptr, bout, CATD, CATD, CATD, DIM, 0,
        (long)NQ * CATD, 0, (long)NQ * DIM, 0, 1.0f);
}

// Round 3
// 691.394 us; speedup vs baseline: 4.3719x; 1.1494x over previous
//
#include <hip/hip_runtime.h>

#define BATCH 16
#define NQ 1024
#define NK 384
#define DIM 768
#define RED 256
#define CATD 1536

typedef __attribute__((ext_vector_type(4))) float f32x4;
typedef __attribute__((ext_vector_type(8))) short short8;

__device__ __forceinline__ short f2bf(float f) {
    unsigned u = __builtin_bit_cast(unsigned, f);
    u = (u + 0x7FFF + ((u >> 16) & 1)) >> 16;
    return (short)u;
}

#define GLOAD_LDS16(g, l) __builtin_amdgcn_global_load_lds( \
    (const __attribute__((address_space(1))) unsigned int*)(g), \
    (__attribute__((address_space(3))) unsigned int*)(l), 16, 0, 0)

// ---------------------------------------------------------------------------
// bf16 MFMA NT GEMM: C = scale * A(MxK) . B(NxK)^T [+ bias]
// 128x128 tile, BK=64, 256 thr, XCD-chunked block swizzle (T1, m204 bijective)
// MODE 0: f32 out; 1: bf16 out; 2: dual f32+bf16; 3: f32 + bias
// ---------------------------------------------------------------------------
template<int MODE>
__global__ __launch_bounds__(256) void gemm_nt_mfma(
    const short* __restrict__ A, const short* __restrict__ B,
    float* __restrict__ Cf, short* __restrict__ Cb,
    const float* __restrict__ bias,
    int K, int lda, int ldb, int ldcf, int ldcb,
    long sA, long sB, long sCf, long sCb, float scale)
{
    __shared__ short Asl[128 * 64];
    __shared__ short Bsl[128 * 64];

    // ---- XCD-aware bijective chunked swizzle (T1) ----
    const unsigned nx = gridDim.x, ny = gridDim.y;
    unsigned lin = (blockIdx.z * ny + blockIdx.y) * nx + blockIdx.x;
    const unsigned nwg = nx * ny * gridDim.z;
    const unsigned qc = nwg >> 3, rc = nwg & 7;
    const unsigned xcd = lin & 7, pos = lin >> 3;
    unsigned nid = (xcd < rc ? xcd * (qc + 1) : rc * (qc + 1) + (xcd - rc) * qc) + pos;
    const unsigned bx = nid % nx;
    unsigned t = nid / nx;
    const unsigned by = t % ny;
    const unsigned bz = t / ny;

    const short* Ab = A + (long)bz * sA;
    const short* Bb = B + (long)bz * sB;
    const int m0 = by * 128, n0 = bx * 128;
    const int tid = threadIdx.x;
    const int lane = tid & 63, wid = tid >> 6;
    const int am0 = (wid >> 1) * 64, bn0 = (wid & 1) * 64;
    const int lr = lane & 15, lg = lane >> 4;

    f32x4 acc[4][4] = {};

    for (int k0 = 0; k0 < K; k0 += 64) {
        #pragma unroll
        for (int i = 0; i < 4; i++) {
            int e = (tid + i * 256) * 8;
            int r = e >> 6, c = e & 63;
            GLOAD_LDS16(Ab + (long)(m0 + r) * lda + k0 + c, Asl + e);
        }
        #pragma unroll
        for (int i = 0; i < 4; i++) {
            int e = (tid + i * 256) * 8;
            int r = e >> 6, c = e & 63;
            GLOAD_LDS16(Bb + (long)(n0 + r) * ldb + k0 + c, Bsl + e);
        }
        __syncthreads();
        #pragma unroll
        for (int ks = 0; ks < 2; ks++) {
            short8 af[4], bfv[4];
            #pragma unroll
            for (int m = 0; m < 4; m++)
                af[m] = *(const short8*)&Asl[(am0 + m * 16 + lr) * 64 + ks * 32 + lg * 8];
            #pragma unroll
            for (int n = 0; n < 4; n++)
                bfv[n] = *(const short8*)&Bsl[(bn0 + n * 16 + lr) * 64 + ks * 32 + lg * 8];
            #pragma unroll
            for (int m = 0; m < 4; m++)
                #pragma unroll
                for (int n = 0; n < 4; n++)
                    acc[m][n] = __builtin_amdgcn_mfma_f32_16x16x32_bf16(
                        af[m], bfv[n], acc[m][n], 0, 0, 0);
        }
        __syncthreads();
    }

    float* Cfb = (MODE != 1) ? Cf + (long)bz * sCf : nullptr;
    short* Cbb = (MODE == 1 || MODE == 2) ? Cb + (long)bz * sCb : nullptr;
    #pragma unroll
    for (int m = 0; m < 4; m++) {
        #pragma unroll
        for (int n = 0; n < 4; n++) {
            int col = n0 + bn0 + n * 16 + lr;
            #pragma unroll
            for (int j = 0; j < 4; j++) {
                long row = m0 + am0 + m * 16 + lg * 4 + j;
                float v = acc[m][n][j] * scale;
                if (MODE == 3) v += bias[col];
                if (MODE != 1) Cfb[row * ldcf + col] = v;
                if (MODE == 1 || MODE == 2) Cbb[row * ldcb + col] = f2bf(v);
            }
        }
    }
}

// ---------------- column sums over tokens (atomic partial) ----------------
__global__ __launch_bounds__(256) void colsum(
    const float* __restrict__ X, float* __restrict__ mean, int N, int chunk)
{
    int b = blockIdx.x;
    int d = blockIdx.y * 256 + threadIdx.x;
    int n0 = blockIdx.z * chunk;
    float s = 0.f;
    for (int n = n0; n < n0 + chunk; n++)
        s += X[((long)b * N + n) * DIM + d];
    atomicAdd(&mean[b * DIM + d], s);
}

// ---------------- center + convert to bf16 ----------------
__global__ __launch_bounds__(256) void center_cvt(
    const float* __restrict__ X, const float* __restrict__ mean,
    short* __restrict__ Xc, int N, float invN)
{
    long i = (long)blockIdx.x * 256 + threadIdx.x;
    long tot8 = (long)BATCH * N * DIM / 8;
    if (i >= tot8) return;
    long e = i * 8;
    int d = (int)(e % DIM);
    int b = (int)(e / ((long)N * DIM));
    const float* mb = mean + b * DIM + d;
    const f32x4* s = (const f32x4*)(X + e);
    f32x4 x0 = s[0], x1 = s[1];
    short8 o;
    o[0] = f2bf(x0[0] - mb[0] * invN);
    o[1] = f2bf(x0[1] - mb[1] * invN);
    o[2] = f2bf(x0[2] - mb[2] * invN);
    o[3] = f2bf(x0[3] - mb[3] * invN);
    o[4] = f2bf(x1[0] - mb[4] * invN);
    o[5] = f2bf(x1[1] - mb[5] * invN);
    o[6] = f2bf(x1[2] - mb[6] * invN);
    o[7] = f2bf(x1[3] - mb[7] * invN);
    *(short8*)(Xc + e) = o;
}

// ---------------- all weights -> bf16 (one launch) ----------------
struct WP { const float* p[7]; };
__global__ __launch_bounds__(256) void cvt_weights(
    WP wp, short* __restrict__ Wqb, short* __restrict__ Wkb,
    short* __restrict__ WoutB)
{
    const int WSZ = RED * DIM / 8;           // 24576 per proj weight
    const int OSZ = DIM * CATD / 8;          // 147456
    int i = blockIdx.x * 256 + threadIdx.x;
    if (i >= 6 * WSZ + OSZ) return;
    const float* src;
    short* dst;
    if (i < 6 * WSZ) {
        int w = i / WSZ, o = i - w * WSZ;
        src = wp.p[w] + (long)o * 8;
        dst = (w < 3 ? Wqb + (long)w * RED * DIM
                     : Wkb + (long)(w - 3) * RED * DIM) + (long)o * 8;
    } else {
        int o = i - 6 * WSZ;
        src = wp.p[6] + (long)o * 8;
        dst = WoutB + (long)o * 8;
    }
    const f32x4* s = (const f32x4*)src;
    f32x4 x0 = s[0], x1 = s[1];
    short8 o8;
    o8[0] = f2bf(x0[0]); o8[1] = f2bf(x0[1]); o8[2] = f2bf(x0[2]); o8[3] = f2bf(x0[3]);
    o8[4] = f2bf(x1[0]); o8[5] = f2bf(x1[1]); o8[6] = f2bf(x1[2]); o8[7] = f2bf(x1[3]);
    *(short8*)dst = o8;
}

// ---------------- transpose + convert: XT[b,d,n] = bf16(X[b,n,d]) ----------------
__global__ __launch_bounds__(256) void transpose_cvt(
    const float* __restrict__ X, short* __restrict__ XT, int N)
{
    __shared__ short tile[32][33];
    int b = blockIdx.z;
    int n0 = blockIdx.x * 32, d0 = blockIdx.y * 32;
    int tx = threadIdx.x & 31, ty = threadIdx.x >> 5;
    const float* Xb = X + (long)b * N * DIM;
    #pragma unroll
    for (int i = 0; i < 4; i++) {
        int n = n0 + ty + i * 8;
        tile[ty + i * 8][tx] = f2bf(Xb[(long)n * DIM + d0 + tx]);
    }
    __syncthreads();
    short* XTb = XT + (long)b * DIM * N;
    #pragma unroll
    for (int i = 0; i < 4; i++) {
        int d = d0 + ty + i * 8;
        XTb[(long)d * N + n0 + tx] = tile[tx][ty + i * 8];
    }
}

// ---------------------------------------------------------------------------
// single-read row softmax: reads S once (register cache), optional bf16 P out,
// optional additive per-batch vector, optional fused dot with lw -> dots[row]
// ---------------------------------------------------------------------------
template<int WRITE_P, int DOT>
__global__ __launch_bounds__(256) void softmax_rows(
    const float* __restrict__ S, short* __restrict__ P,
    const float* __restrict__ addv, const float* __restrict__ lw,
    float* __restrict__ dots, int L, int rows_per_batch)
{
    long row = blockIdx.x;
    const float* p = S + row * (long)L;
    const int tid = threadIdx.x;
    const int C = (L + 255) >> 8;   // <=4
    float v[4];
    float mx = -3.0e38f;
    for (int c = 0; c < C; c++) {
        int i = tid + c * 256;
        v[c] = (i < L) ? p[i] : -3.0e38f;
        mx = fmaxf(mx, v[c]);
    }
    __shared__ float rmax[4], rsum[4], rdot[4];
    #pragma unroll
    for (int o = 1; o < 64; o <<= 1) mx = fmaxf(mx, __shfl_xor(mx, o));
    if ((tid & 63) == 0) rmax[tid >> 6] = mx;
    __syncthreads();
    mx = fmaxf(fmaxf(rmax[0], rmax[1]), fmaxf(rmax[2], rmax[3]));
    float s = 0.f, dt = 0.f;
    for (int c = 0; c < C; c++) {
        int i = tid + c * 256;
        float e = expf(v[c] - mx);
        v[c] = e;
        s += e;
        if (DOT) dt += (i < L) ? e * lw[i] : 0.f;
    }
    #pragma unroll
    for (int o = 1; o < 64; o <<= 1) s += __shfl_xor(s, o);
    if ((tid & 63) == 0) rsum[tid >> 6] = s;
    if (DOT) {
        #pragma unroll
        for (int o = 1; o < 64; o <<= 1) dt += __shfl_xor(dt, o);
        if ((tid & 63) == 0) rdot[tid >> 6] = dt;
    }
    __syncthreads();
    s = rsum[0] + rsum[1] + rsum[2] + rsum[3];
    float inv = 1.0f / s;
    if (DOT && tid == 0)
        dots[row] = (rdot[0] + rdot[1] + rdot[2] + rdot[3]) * inv;
    if (WRITE_P) {
        short* po = P + row * (long)L;
        if (addv) {
            int b = (int)(row / rows_per_batch);
            const float* av = addv + (long)b * L;
            for (int c = 0; c < C; c++) {
                int i = tid + c * 256;
                if (i < L) po[i] = f2bf(v[c] * inv + av[i]);
            }
        } else {
            for (int c = 0; c < C; c++) {
                int i = tid + c * 256;
                if (i < L) po[i] = f2bf(v[c] * inv);
            }
        }
    }
}

// ---------------- hid[b,n] = softmax_n(scores[b,n]) (lb shift cancels) ----------------
__global__ __launch_bounds__(384) void hid_softmax(
    const float* __restrict__ scores, float* __restrict__ hid)
{
    int b = blockIdx.x;
    int n = threadIdx.x; // 0..383
    float s = scores[b * NK + n];
    __shared__ float red[6];
    float mx = s;
    #pragma unroll
    for (int o = 1; o < 64; o <<= 1) mx = fmaxf(mx, __shfl_xor(mx, o));
    int wid = n >> 6;
    if ((n & 63) == 0) red[wid] = mx;
    __syncthreads();
    mx = red[0];
    #pragma unroll
    for (int w = 1; w < 6; w++) mx = fmaxf(mx, red[w]);
    float e = expf(s - mx);
    float sm = e;
    #pragma unroll
    for (int o = 1; o < 64; o <<= 1) sm += __shfl_xor(sm, o);
    __syncthreads();
    if ((n & 63) == 0) red[wid] = sm;
    __syncthreads();
    sm = 0.f;
    #pragma unroll
    for (int w = 0; w < 6; w++) sm += red[w];
    hid[b * NK + n] = e / sm;
}

extern "C" void kernel_launch(void* const* d_in, const int* in_sizes, int n_in,
                              void* d_out, int out_size, void* d_ws, size_t ws_size,
                              hipStream_t stream)
{
    const float* Qf  = (const float*)d_in[0];
    const float* If  = (const float*)d_in[1];
    const float* lw  = (const float*)d_in[14];
    const float* bout= (const float*)d_in[17];

    float* cat = (float*)d_out;                              // [B,NQ,1536]
    float* out = (float*)d_out + (long)BATCH * NQ * CATD;    // [B,NQ,768]

    char* ws = (char*)d_ws;
    size_t off = 0;
    auto alloc = [&](size_t bytes) { char* p = ws + off; off += (bytes + 255) & ~(size_t)255; return p; };

    float* S     = (float*)alloc((size_t)BATCH * NQ * NQ * 4);   // reused S1/S2/S3
    short* Qc    = (short*)alloc((size_t)BATCH * NQ * DIM * 2);  // later aliased as QfT
    short* Kc    = (short*)alloc((size_t)BATCH * NK * DIM * 2);  // later aliased as IfT
    short* q_all = (short*)alloc((size_t)BATCH * NQ * 3 * RED * 2); // [B*NQ,768] q1|q2|q3
    short* k_all = (short*)alloc((size_t)BATCH * NK * 3 * RED * 2); // [B*NK,768]
    short* P1    = (short*)alloc((size_t)BATCH * NQ * NQ * 2);
    short* P3    = (short*)alloc((size_t)BATCH * NQ * NK * 2);
    short* catbf = (short*)alloc((size_t)BATCH * NQ * CATD * 2);
    short* Wqb   = (short*)alloc((size_t)3 * RED * DIM * 2);     // [768,768] stacked
    short* Wkb   = (short*)alloc((size_t)3 * RED * DIM * 2);
    short* WoutB = (short*)alloc((size_t)DIM * CATD * 2);
    float* means = (float*)alloc((size_t)2 * BATCH * DIM * 4);   // meanQ | meanK
    float* scores= (float*)alloc((size_t)BATCH * NK * 4);
    float* hid   = (float*)alloc((size_t)BATCH * NK * 4);

    float* meanQ = means;
    float* meanK = means + BATCH * DIM;
    short* QfT = Qc;  // [B, DIM, NQ] — alias, Qc dead after projections
    short* IfT = Kc;  // [B, DIM, NK]

    hipMemsetAsync(means, 0, (size_t)2 * BATCH * DIM * 4, stream);

    // means of raw inputs over token axis
    colsum<<<dim3(BATCH, DIM / 256, NQ / 128), 256, 0, stream>>>(Qf, meanQ, NQ, 128);
    colsum<<<dim3(BATCH, DIM / 256, NK / 128), 256, 0, stream>>>(If, meanK, NK, 128);
    // centered bf16 inputs (bias cancels under centering)
    center_cvt<<<(BATCH * NQ * DIM / 8 + 255) / 256, 256, 0, stream>>>(Qf, meanQ, Qc, NQ, 1.0f / NQ);
    center_cvt<<<(BATCH * NK * DIM / 8 + 255) / 256, 256, 0, stream>>>(If, meanK, Kc, NK, 1.0f / NK);

    // all weights -> bf16 (Wq1..3 stacked into Wqb, Wk1..3 into Wkb)
    {
        WP wp;
        wp.p[0] = (const float*)d_in[2];   // Wq1
        wp.p[1] = (const float*)d_in[4];   // Wq2
        wp.p[2] = (const float*)d_in[6];   // Wq3
        wp.p[3] = (const float*)d_in[8];   // Wk1
        wp.p[4] = (const float*)d_in[10];  // Wk2
        wp.p[5] = (const float*)d_in[12];  // Wk3
        wp.p[6] = (const float*)d_in[16];  // Wout
        int total = 6 * (RED * DIM / 8) + DIM * CATD / 8;
        cvt_weights<<<(total + 255) / 256, 256, 0, stream>>>(wp, Wqb, Wkb, WoutB);
    }

    // merged projections: q_all = Qc(16384x768) . Wqb(768x768)^T, k_all likewise
    gemm_nt_mfma<1><<<dim3(6, BATCH * NQ / 128, 1), 256, 0, stream>>>(
        Qc, Wqb, nullptr, q_all, nullptr,
        DIM, DIM, DIM, 0, 3 * RED, 0, 0, 0, 0, 1.0f);
    gemm_nt_mfma<1><<<dim3(6, BATCH * NK / 128, 1), 256, 0, stream>>>(
        Kc, Wkb, nullptr, k_all, nullptr,
        DIM, DIM, DIM, 0, 3 * RED, 0, 0, 0, 0, 1.0f);

    // transposed raw inputs for PV (overwrites Qc/Kc — dead after projections)
    transpose_cvt<<<dim3(NQ / 32, DIM / 32, BATCH), 256, 0, stream>>>(Qf, QfT, NQ);
    transpose_cvt<<<dim3(NK / 32, DIM / 32, BATCH), 256, 0, stream>>>(If, IfT, NK);

    const float scale = 0.0625f; // 1/sqrt(256)
    const short* q1 = q_all;            // col offsets in [B*NQ,768]
    const short* q2 = q_all + RED;
    const short* q3 = q_all + 2 * RED;
    const short* k1 = k_all;
    const short* k2 = k_all + RED;
    const short* k3 = k_all + 2 * RED;
    const long sQ = (long)NQ * 3 * RED, sK = (long)NK * 3 * RED;

    // aw1 = softmax(q1.q2^T/16) -> P1 bf16
    gemm_nt_mfma<0><<<dim3(NQ / 128, NQ / 128, BATCH), 256, 0, stream>>>(
        q1, q2, S, nullptr, nullptr, RED, 3 * RED, 3 * RED, NQ, 0,
        sQ, sQ, (long)NQ * NQ, 0, scale);
    softmax_rows<1, 0><<<BATCH * NQ, 256, 0, stream>>>(S, P1, nullptr, nullptr, nullptr, NQ, NQ);

    // aw2 path: S2 = k1.k2^T/16; fused softmax+dot(lw) -> scores; P2 never stored
    gemm_nt_mfma<0><<<dim3(NK / 128, NK / 128, BATCH), 256, 0, stream>>>(
        k1, k2, S, nullptr, nullptr, RED, 3 * RED, 3 * RED, NK, 0,
        sK, sK, (long)NK * NK, 0, scale);
    softmax_rows<0, 1><<<BATCH * NK, 256, 0, stream>>>(S, nullptr, nullptr, lw, scores, NK, NK);
    hid_softmax<<<BATCH, NK, 0, stream>>>(scores, hid);

    // aw3 = softmax(q3.k3^T/16) + hid -> P3 bf16
    gemm_nt_mfma<0><<<dim3(NK / 128, NQ / 128, BATCH), 256, 0, stream>>>(
        q3, k3, S, nullptr, nullptr, RED, 3 * RED, 3 * RED, NK, 0,
        sQ, sK, (long)NQ * NK, 0, scale);
    softmax_rows<1, 0><<<BATCH * NQ, 256, 0, stream>>>(S, P3, hid, nullptr, nullptr, NK, NQ);

    // attention_feature1 = P1 . QfT^T -> cat[:, :768] (f32) + catbf
    gemm_nt_mfma<2><<<dim3(DIM / 128, NQ / 128, BATCH), 256, 0, stream>>>(
        P1, QfT, cat, catbf, nullptr, NQ, NQ, NQ, CATD, CATD,
        (long)NQ * NQ, (long)DIM * NQ, (long)NQ * CATD, (long)NQ * CATD, 1.0f);
    // attention_feature2 = P3 . IfT^T -> cat[:, 768:] + catbf
    gemm_nt_mfma<2><<<dim3(DIM / 128, NQ / 128, BATCH), 256, 0, stream>>>(
        P3, IfT, cat + DIM, catbf + DIM, nullptr, NK, NK, NK, CATD, CATD,
        (long)NQ * NK, (long)DIM * NK, (long)NQ * CATD, (long)NQ * CATD, 1.0f);

    // out = catbf . Wout^T + bout
    gemm_nt_mfma<3><<<dim3(DIM / 128, NQ / 128, BATCH), 256, 0, stream>>>(
        catbf, WoutB, out, nullptr, bout, CATD, CATD, CATD, DIM, 0,
        (long)NQ * CATD, 0, (long)NQ * DIM, 0, 1.0f);
}

// Round 4
// 666.691 us; speedup vs baseline: 4.5339x; 1.0371x over previous
//
#include <hip/hip_runtime.h>

#define BATCH 16
#define NQ 1024
#define NK 384
#define DIM 768
#define RED 256
#define CATD 1536

typedef __attribute__((ext_vector_type(4))) float f32x4;
typedef __attribute__((ext_vector_type(8))) short short8;

__device__ __forceinline__ short f2bf(float f) {
    unsigned u = __builtin_bit_cast(unsigned, f);
    u = (u + 0x7FFF + ((u >> 16) & 1)) >> 16;
    return (short)u;
}

#define GLOAD_LDS16(g, l) __builtin_amdgcn_global_load_lds( \
    (const __attribute__((address_space(1))) unsigned int*)(g), \
    (__attribute__((address_space(3))) unsigned int*)(l), 16, 0, 0)

// ---------------------------------------------------------------------------
// Descriptor-routed bf16 MFMA NT GEMM: C = scale * A(MxK).B(NxK)^T [+bias]
// 128x128 tile, BK=64, 4 waves, double-buffered LDS (2-phase schedule),
// T1 bijective XCD swizzle on the flat grid. Up to 3 segments per launch.
// Output: f32 (Cf, +bias if set) and/or bf16 (Cb).
// ---------------------------------------------------------------------------
struct GemmDesc {
    const short* A; const short* B;
    float* Cf; short* Cb; const float* bias;
    int K, lda, ldb, ldcf, ldcb;
    long sA, sB, sCf, sCb;
    float scale;
    int nx, ny;     // x-tiles (N/128), y-tiles (M/128); z = batches
    int start;      // flat block offset of this segment
};

__global__ __launch_bounds__(256) void gemm_routed(
    GemmDesc d0, GemmDesc d1, GemmDesc d2, int nseg)
{
    __shared__ short Asl[2][128 * 64];
    __shared__ short Bsl[2][128 * 64];

    // T1 bijective chunked swizzle over the flat grid
    unsigned lin = blockIdx.x;
    const unsigned nwg = gridDim.x;
    const unsigned qc = nwg >> 3, rc = nwg & 7;
    const unsigned xcd = lin & 7, pos = lin >> 3;
    unsigned nid = (xcd < rc ? xcd * (qc + 1) : rc * (qc + 1) + (xcd - rc) * qc) + pos;

    GemmDesc d = d0;
    if (nseg > 1 && nid >= (unsigned)d1.start) d = d1;
    if (nseg > 2 && nid >= (unsigned)d2.start) d = d2;

    unsigned r = nid - (unsigned)d.start;
    const unsigned bx = r % (unsigned)d.nx; r /= (unsigned)d.nx;
    const unsigned by = r % (unsigned)d.ny;
    const unsigned bz = r / (unsigned)d.ny;

    const short* Ab = d.A + (long)bz * d.sA;
    const short* Bb = d.B + (long)bz * d.sB;
    const int m0 = by * 128, n0 = bx * 128;
    const int tid = threadIdx.x;
    const int lane = tid & 63, wid = tid >> 6;
    const int am0 = (wid >> 1) * 64, bn0 = (wid & 1) * 64;
    const int lr = lane & 15, lg = lane >> 4;
    const int lda = d.lda, ldb = d.ldb;

    f32x4 acc[4][4] = {};

    auto stage = [&](int buf, int k0) {
        #pragma unroll
        for (int i = 0; i < 4; i++) {
            int e = (tid + i * 256) * 8;
            int rr = e >> 6, c = e & 63;
            GLOAD_LDS16(Ab + (long)(m0 + rr) * lda + k0 + c, &Asl[buf][e]);
        }
        #pragma unroll
        for (int i = 0; i < 4; i++) {
            int e = (tid + i * 256) * 8;
            int rr = e >> 6, c = e & 63;
            GLOAD_LDS16(Bb + (long)(n0 + rr) * ldb + k0 + c, &Bsl[buf][e]);
        }
    };
    auto compute = [&](int buf) {
        #pragma unroll
        for (int ks = 0; ks < 2; ks++) {
            short8 af[4], bfv[4];
            #pragma unroll
            for (int m = 0; m < 4; m++)
                af[m] = *(const short8*)&Asl[buf][(am0 + m * 16 + lr) * 64 + ks * 32 + lg * 8];
            #pragma unroll
            for (int n = 0; n < 4; n++)
                bfv[n] = *(const short8*)&Bsl[buf][(bn0 + n * 16 + lr) * 64 + ks * 32 + lg * 8];
            #pragma unroll
            for (int m = 0; m < 4; m++)
                #pragma unroll
                for (int n = 0; n < 4; n++)
                    acc[m][n] = __builtin_amdgcn_mfma_f32_16x16x32_bf16(
                        af[m], bfv[n], acc[m][n], 0, 0, 0);
        }
    };

    // 2-phase double-buffered pipeline: stage(t+1) overlaps compute(t)
    const int nt = d.K >> 6;
    stage(0, 0);
    __syncthreads();                 // vmcnt(0) drain + barrier: buf0 ready
    int cur = 0;
    for (int t = 0; t < nt; ++t) {
        if (t + 1 < nt) stage(cur ^ 1, (t + 1) << 6);
        compute(cur);
        if (t + 1 < nt) { __syncthreads(); cur ^= 1; }
    }

    // epilogue
    const float scale = d.scale;
    float* Cfb = d.Cf ? d.Cf + (long)bz * d.sCf : nullptr;
    short* Cbb = d.Cb ? d.Cb + (long)bz * d.sCb : nullptr;
    if (Cfb && Cbb) {
        #pragma unroll
        for (int m = 0; m < 4; m++)
            #pragma unroll
            for (int n = 0; n < 4; n++) {
                int col = n0 + bn0 + n * 16 + lr;
                #pragma unroll
                for (int j = 0; j < 4; j++) {
                    long row = m0 + am0 + m * 16 + lg * 4 + j;
                    float v = acc[m][n][j] * scale;
                    Cfb[row * d.ldcf + col] = v;
                    Cbb[row * d.ldcb + col] = f2bf(v);
                }
            }
    } else if (Cfb) {
        const float* bias = d.bias;
        #pragma unroll
        for (int m = 0; m < 4; m++)
            #pragma unroll
            for (int n = 0; n < 4; n++) {
                int col = n0 + bn0 + n * 16 + lr;
                float bv = bias ? bias[col] : 0.f;
                #pragma unroll
                for (int j = 0; j < 4; j++) {
                    long row = m0 + am0 + m * 16 + lg * 4 + j;
                    Cfb[row * d.ldcf + col] = acc[m][n][j] * scale + bv;
                }
            }
    } else {
        #pragma unroll
        for (int m = 0; m < 4; m++)
            #pragma unroll
            for (int n = 0; n < 4; n++) {
                int col = n0 + bn0 + n * 16 + lr;
                #pragma unroll
                for (int j = 0; j < 4; j++) {
                    long row = m0 + am0 + m * 16 + lg * 4 + j;
                    Cbb[row * d.ldcb + col] = f2bf(acc[m][n][j] * scale);
                }
            }
    }
}

// ---------------- column sums over tokens (atomic partial) ----------------
__global__ __launch_bounds__(256) void colsum(
    const float* __restrict__ X, float* __restrict__ mean, int N, int chunk)
{
    int b = blockIdx.x;
    int dd = blockIdx.y * 256 + threadIdx.x;
    int n0 = blockIdx.z * chunk;
    float s = 0.f;
    for (int n = n0; n < n0 + chunk; n++)
        s += X[((long)b * N + n) * DIM + dd];
    atomicAdd(&mean[b * DIM + dd], s);
}

// ------- fused: centered bf16 row-major (Xc) + raw bf16 transpose (XT) -------
template<int N>
__global__ __launch_bounds__(256) void prep_input(
    const float* __restrict__ X, const float* __restrict__ mean,
    short* __restrict__ Xc, short* __restrict__ XT, float invN)
{
    __shared__ short tile[32][33];
    int b = blockIdx.z;
    int n0 = blockIdx.x * 32, d0 = blockIdx.y * 32;
    int tx = threadIdx.x & 31, ty = threadIdx.x >> 5;
    const float* Xb = X + (long)b * N * DIM;
    short* Xcb = Xc + (long)b * N * DIM;
    float mv = mean[b * DIM + d0 + tx] * invN;
    #pragma unroll
    for (int i = 0; i < 4; i++) {
        int n = n0 + ty + i * 8;
        float x = Xb[(long)n * DIM + d0 + tx];
        tile[ty + i * 8][tx] = f2bf(x);
        Xcb[(long)n * DIM + d0 + tx] = f2bf(x - mv);
    }
    __syncthreads();
    short* XTb = XT + (long)b * DIM * N;
    #pragma unroll
    for (int i = 0; i < 4; i++) {
        int dd = d0 + ty + i * 8;
        XTb[(long)dd * N + n0 + tx] = tile[tx][ty + i * 8];
    }
}

// ---------------- all weights -> bf16 (one launch) ----------------
struct WP { const float* p[7]; };
__global__ __launch_bounds__(256) void cvt_weights(
    WP wp, short* __restrict__ Wqb, short* __restrict__ Wkb,
    short* __restrict__ WoutB)
{
    const int WSZ = RED * DIM / 8;
    const int OSZ = DIM * CATD / 8;
    int i = blockIdx.x * 256 + threadIdx.x;
    if (i >= 6 * WSZ + OSZ) return;
    const float* src;
    short* dst;
    if (i < 6 * WSZ) {
        int w = i / WSZ, o = i - w * WSZ;
        src = wp.p[w] + (long)o * 8;
        dst = (w < 3 ? Wqb + (long)w * RED * DIM
                     : Wkb + (long)(w - 3) * RED * DIM) + (long)o * 8;
    } else {
        int o = i - 6 * WSZ;
        src = wp.p[6] + (long)o * 8;
        dst = WoutB + (long)o * 8;
    }
    const f32x4* s = (const f32x4*)src;
    f32x4 x0 = s[0], x1 = s[1];
    short8 o8;
    o8[0] = f2bf(x0[0]); o8[1] = f2bf(x0[1]); o8[2] = f2bf(x0[2]); o8[3] = f2bf(x0[3]);
    o8[4] = f2bf(x1[0]); o8[5] = f2bf(x1[1]); o8[6] = f2bf(x1[2]); o8[7] = f2bf(x1[3]);
    *(short8*)dst = o8;
}

// ---------------- softmax device body (compile-time L) ----------------
template<int L>
__device__ __forceinline__ void softmax_body(
    const float* __restrict__ p, short* __restrict__ po,
    const float* __restrict__ addv)
{
    const int tid = threadIdx.x;
    const int C = (L + 255) >> 8;
    float v[C];
    float mx = -3.0e38f;
    #pragma unroll
    for (int c = 0; c < C; c++) {
        int i = tid + c * 256;
        v[c] = (i < L) ? p[i] : -3.0e38f;
        mx = fmaxf(mx, v[c]);
    }
    __shared__ float rmax[4], rsum[4];
    #pragma unroll
    for (int o = 1; o < 64; o <<= 1) mx = fmaxf(mx, __shfl_xor(mx, o));
    if ((tid & 63) == 0) rmax[tid >> 6] = mx;
    __syncthreads();
    mx = fmaxf(fmaxf(rmax[0], rmax[1]), fmaxf(rmax[2], rmax[3]));
    float s = 0.f;
    #pragma unroll
    for (int c = 0; c < C; c++) {
        float e = __expf(v[c] - mx);
        v[c] = e;
        s += e;
    }
    #pragma unroll
    for (int o = 1; o < 64; o <<= 1) s += __shfl_xor(s, o);
    if ((tid & 63) == 0) rsum[tid >> 6] = s;
    __syncthreads();
    s = rsum[0] + rsum[1] + rsum[2] + rsum[3];
    float inv = 1.0f / s;
    if (addv) {
        #pragma unroll
        for (int c = 0; c < C; c++) {
            int i = tid + c * 256;
            if (i < L) po[i] = f2bf(v[c] * inv + addv[i]);
        }
    } else {
        #pragma unroll
        for (int c = 0; c < C; c++) {
            int i = tid + c * 256;
            if (i < L) po[i] = f2bf(v[c] * inv);
        }
    }
}

// ---- merged softmax: rows [0,B*NQ) -> P1 (L=NQ); rows [B*NQ,..) -> P3 (L=NK, +hid)
__global__ __launch_bounds__(256) void softmax_two(
    const float* __restrict__ S1, short* __restrict__ P1,
    const float* __restrict__ S3, short* __restrict__ P3,
    const float* __restrict__ hid)
{
    long row = blockIdx.x;
    if (row < (long)BATCH * NQ) {
        softmax_body<NQ>(S1 + row * NQ, P1 + row * NQ, nullptr);
    } else {
        row -= (long)BATCH * NQ;
        int b = (int)(row / NQ);
        softmax_body<NK>(S3 + row * NK, P3 + row * NK, hid + (long)b * NK);
    }
}

// ---- softmax+dot for S2: scores[row] = (softmax(S2 row)) . lw  ----
__global__ __launch_bounds__(256) void softmax_dot(
    const float* __restrict__ S2, const float* __restrict__ lw,
    float* __restrict__ scores)
{
    long row = blockIdx.x;
    const float* p = S2 + row * NK;
    const int tid = threadIdx.x;
    const int C = 2;
    float v[C];
    float mx = -3.0e38f;
    #pragma unroll
    for (int c = 0; c < C; c++) {
        int i = tid + c * 256;
        v[c] = (i < NK) ? p[i] : -3.0e38f;
        mx = fmaxf(mx, v[c]);
    }
    __shared__ float rmax[4], rsum[4], rdot[4];
    #pragma unroll
    for (int o = 1; o < 64; o <<= 1) mx = fmaxf(mx, __shfl_xor(mx, o));
    if ((tid & 63) == 0) rmax[tid >> 6] = mx;
    __syncthreads();
    mx = fmaxf(fmaxf(rmax[0], rmax[1]), fmaxf(rmax[2], rmax[3]));
    float s = 0.f, dt = 0.f;
    #pragma unroll
    for (int c = 0; c < C; c++) {
        int i = tid + c * 256;
        float e = __expf(v[c] - mx);
        s += e;
        dt += (i < NK) ? e * lw[i] : 0.f;
    }
    #pragma unroll
    for (int o = 1; o < 64; o <<= 1) { s += __shfl_xor(s, o); dt += __shfl_xor(dt, o); }
    if ((tid & 63) == 0) { rsum[tid >> 6] = s; rdot[tid >> 6] = dt; }
    __syncthreads();
    if (tid == 0) {
        s = rsum[0] + rsum[1] + rsum[2] + rsum[3];
        dt = rdot[0] + rdot[1] + rdot[2] + rdot[3];
        scores[row] = dt / s;
    }
}

// ---------------- hid[b,n] = softmax_n(scores[b,n]) ----------------
__global__ __launch_bounds__(384) void hid_softmax(
    const float* __restrict__ scores, float* __restrict__ hid)
{
    int b = blockIdx.x;
    int n = threadIdx.x;
    float s = scores[b * NK + n];
    __shared__ float red[6];
    float mx = s;
    #pragma unroll
    for (int o = 1; o < 64; o <<= 1) mx = fmaxf(mx, __shfl_xor(mx, o));
    int wid = n >> 6;
    if ((n & 63) == 0) red[wid] = mx;
    __syncthreads();
    mx = red[0];
    #pragma unroll
    for (int w = 1; w < 6; w++) mx = fmaxf(mx, red[w]);
    float e = __expf(s - mx);
    float sm = e;
    #pragma unroll
    for (int o = 1; o < 64; o <<= 1) sm += __shfl_xor(sm, o);
    __syncthreads();
    if ((n & 63) == 0) red[wid] = sm;
    __syncthreads();
    sm = 0.f;
    #pragma unroll
    for (int w = 0; w < 6; w++) sm += red[w];
    hid[b * NK + n] = e / sm;
}

extern "C" void kernel_launch(void* const* d_in, const int* in_sizes, int n_in,
                              void* d_out, int out_size, void* d_ws, size_t ws_size,
                              hipStream_t stream)
{
    const float* Qf  = (const float*)d_in[0];
    const float* If  = (const float*)d_in[1];
    const float* lw  = (const float*)d_in[14];
    const float* bout= (const float*)d_in[17];

    float* cat = (float*)d_out;                              // [B,NQ,1536]
    float* out = (float*)d_out + (long)BATCH * NQ * CATD;    // [B,NQ,768]

    char* ws = (char*)d_ws;
    size_t off = 0;
    auto alloc = [&](size_t bytes) { char* p = ws + off; off += (bytes + 255) & ~(size_t)255; return p; };

    float* S1    = (float*)alloc((size_t)BATCH * NQ * NQ * 4);
    float* S2    = (float*)alloc((size_t)BATCH * NK * NK * 4);
    float* S3    = (float*)alloc((size_t)BATCH * NQ * NK * 4);
    short* Qc    = (short*)alloc((size_t)BATCH * NQ * DIM * 2);
    short* Kc    = (short*)alloc((size_t)BATCH * NK * DIM * 2);
    short* QfT   = (short*)alloc((size_t)BATCH * NQ * DIM * 2);
    short* IfT   = (short*)alloc((size_t)BATCH * NK * DIM * 2);
    short* q_all = (short*)alloc((size_t)BATCH * NQ * 3 * RED * 2);
    short* k_all = (short*)alloc((size_t)BATCH * NK * 3 * RED * 2);
    short* P1    = (short*)alloc((size_t)BATCH * NQ * NQ * 2);
    short* P3    = (short*)alloc((size_t)BATCH * NQ * NK * 2);
    short* catbf = (short*)alloc((size_t)BATCH * NQ * CATD * 2);
    short* Wqb   = (short*)alloc((size_t)3 * RED * DIM * 2);
    short* Wkb   = (short*)alloc((size_t)3 * RED * DIM * 2);
    short* WoutB = (short*)alloc((size_t)DIM * CATD * 2);
    float* means = (float*)alloc((size_t)2 * BATCH * DIM * 4);
    float* scores= (float*)alloc((size_t)BATCH * NK * 4);
    float* hid   = (float*)alloc((size_t)BATCH * NK * 4);

    float* meanQ = means;
    float* meanK = means + BATCH * DIM;

    hipMemsetAsync(means, 0, (size_t)2 * BATCH * DIM * 4, stream);

    colsum<<<dim3(BATCH, DIM / 256, NQ / 128), 256, 0, stream>>>(Qf, meanQ, NQ, 128);
    colsum<<<dim3(BATCH, DIM / 256, NK / 128), 256, 0, stream>>>(If, meanK, NK, 128);

    prep_input<NQ><<<dim3(NQ / 32, DIM / 32, BATCH), 256, 0, stream>>>(Qf, meanQ, Qc, QfT, 1.0f / NQ);
    prep_input<NK><<<dim3(NK / 32, DIM / 32, BATCH), 256, 0, stream>>>(If, meanK, Kc, IfT, 1.0f / NK);

    {
        WP wp;
        wp.p[0] = (const float*)d_in[2];
        wp.p[1] = (const float*)d_in[4];
        wp.p[2] = (const float*)d_in[6];
        wp.p[3] = (const float*)d_in[8];
        wp.p[4] = (const float*)d_in[10];
        wp.p[5] = (const float*)d_in[12];
        wp.p[6] = (const float*)d_in[16];
        int total = 6 * (RED * DIM / 8) + DIM * CATD / 8;
        cvt_weights<<<(total + 255) / 256, 256, 0, stream>>>(wp, Wqb, Wkb, WoutB);
    }

    const float scale = 0.0625f; // 1/sqrt(256)
    const long sQ = (long)NQ * 3 * RED, sK = (long)NK * 3 * RED;
    GemmDesc z = {};

    // ---- merged projections: Qc.Wqb^T -> q_all ; Kc.Wkb^T -> k_all ----
    {
        GemmDesc dq = z, dk = z;
        dq.A = Qc; dq.B = Wqb; dq.Cb = q_all;
        dq.K = DIM; dq.lda = DIM; dq.ldb = DIM; dq.ldcb = 3 * RED;
        dq.scale = 1.0f; dq.nx = 6; dq.ny = BATCH * NQ / 128; dq.start = 0;
        dk = dq; dk.A = Kc; dk.B = Wkb; dk.Cb = k_all;
        dk.ny = BATCH * NK / 128; dk.start = 6 * (BATCH * NQ / 128);
        int total = dk.start + 6 * (BATCH * NK / 128);
        gemm_routed<<<total, 256, 0, stream>>>(dq, dk, z, 2);
    }

    // ---- merged score GEMMs: S1 = q1.q2^T/16, S2 = k1.k2^T/16, S3 = q3.k3^T/16
    {
        GemmDesc a = z, b = z, c = z;
        a.A = q_all; a.B = q_all + RED; a.Cf = S1;
        a.K = RED; a.lda = 3 * RED; a.ldb = 3 * RED; a.ldcf = NQ;
        a.sA = sQ; a.sB = sQ; a.sCf = (long)NQ * NQ;
        a.scale = scale; a.nx = NQ / 128; a.ny = NQ / 128; a.start = 0;
        b.A = k_all; b.B = k_all + RED; b.Cf = S2;
        b.K = RED; b.lda = 3 * RED; b.ldb = 3 * RED; b.ldcf = NK;
        b.sA = sK; b.sB = sK; b.sCf = (long)NK * NK;
        b.scale = scale; b.nx = NK / 128; b.ny = NK / 128;
        b.start = a.nx * a.ny * BATCH;
        c.A = q_all + 2 * RED; c.B = k_all + 2 * RED; c.Cf = S3;
        c.K = RED; c.lda = 3 * RED; c.ldb = 3 * RED; c.ldcf = NK;
        c.sA = sQ; c.sB = sK; c.sCf = (long)NQ * NK;
        c.scale = scale; c.nx = NK / 128; c.ny = NQ / 128;
        c.start = b.start + b.nx * b.ny * BATCH;
        int total = c.start + c.nx * c.ny * BATCH;
        gemm_routed<<<total, 256, 0, stream>>>(a, b, c, 3);
    }

    softmax_dot<<<BATCH * NK, 256, 0, stream>>>(S2, lw, scores);
    hid_softmax<<<BATCH, NK, 0, stream>>>(scores, hid);
    softmax_two<<<2 * BATCH * NQ, 256, 0, stream>>>(S1, P1, S3, P3, hid);

    // ---- merged PV: cat[:, :768] = P1.QfT^T ; cat[:, 768:] = P3.IfT^T (dual f32+bf16)
    {
        GemmDesc p1 = z, p2 = z;
        p1.A = P1; p1.B = QfT; p1.Cf = cat; p1.Cb = catbf;
        p1.K = NQ; p1.lda = NQ; p1.ldb = NQ; p1.ldcf = CATD; p1.ldcb = CATD;
        p1.sA = (long)NQ * NQ; p1.sB = (long)DIM * NQ;
        p1.sCf = (long)NQ * CATD; p1.sCb = (long)NQ * CATD;
        p1.scale = 1.0f; p1.nx = DIM / 128; p1.ny = NQ / 128; p1.start = 0;
        p2 = p1;
        p2.A = P3; p2.B = IfT; p2.Cf = cat + DIM; p2.Cb = catbf + DIM;
        p2.K = NK; p2.lda = NK; p2.ldb = NK;
        p2.sA = (long)NQ * NK; p2.sB = (long)DIM * NK;
        p2.start = p1.nx * p1.ny * BATCH;
        int total = 2 * p1.nx * p1.ny * BATCH;
        gemm_routed<<<total, 256, 0, stream>>>(p1, p2, z, 2);
    }

    // ---- final: out = catbf.Wout^T + bout ----
    {
        GemmDesc f = z;
        f.A = catbf; f.B = WoutB; f.Cf = out; f.bias = bout;
        f.K = CATD; f.lda = CATD; f.ldb = CATD; f.ldcf = DIM;
        f.scale = 1.0f; f.nx = DIM / 128; f.ny = BATCH * NQ / 128; f.start = 0;
        gemm_routed<<<f.nx * f.ny, 256, 0, stream>>>(f, z, z, 1);
    }
}